// Round 3
// baseline (7627.135 us; speedup 1.0000x reference)
//
#include <hip/hip_runtime.h>
#include <math.h>

#define DEPTH 4
#define C 128
#define P 17
#define HID 256
#define SPB 2
#define ROWS 34          // SPB*P
#define LS 132           // fp32 LDS row stride (pad vs 128)
#define QS 136           // bf16 q/k/v row stride
#define SEGQ (ROWS*QS)   // 4624

__device__ __forceinline__ unsigned short f2bf(float f) {
    unsigned int u = __float_as_uint(f);
    u += 0x7FFFu + ((u >> 16) & 1u);
    return (unsigned short)(u >> 16);
}
__device__ __forceinline__ void unpack8(uint4 u, float* f) {
    f[0] = __uint_as_float(u.x << 16); f[1] = __uint_as_float(u.x & 0xffff0000u);
    f[2] = __uint_as_float(u.y << 16); f[3] = __uint_as_float(u.y & 0xffff0000u);
    f[4] = __uint_as_float(u.z << 16); f[5] = __uint_as_float(u.z & 0xffff0000u);
    f[6] = __uint_as_float(u.w << 16); f[7] = __uint_as_float(u.w & 0xffff0000u);
}

// MODE 0 = ln1 (+gate), 1 = ln2, 2 = final->out. fp32 everywhere.
template<int MODE>
__device__ __forceinline__ void ln_stage(const float* h_s, float* dst, float* gate_s,
        const float* __restrict__ g, const float* __restrict__ b,
        const float* __restrict__ wg, float bgate,
        float* __restrict__ outp, int tok0, int wave, int lane)
{
    int half = lane >> 5, l2 = lane & 31;
    #pragma unroll
    for (int it = 0; it < 5; ++it) {
        int row = it * 8 + wave * 2 + half;   // 0..39, each once
        if (row < ROWS) {
            float4 v = *(const float4*)&h_s[row * LS + l2 * 4];
            float s  = v.x + v.y + v.z + v.w;
            float ss = v.x*v.x + v.y*v.y + v.z*v.z + v.w*v.w;
            #pragma unroll
            for (int o = 16; o > 0; o >>= 1) { s += __shfl_xor(s, o, 32); ss += __shfl_xor(ss, o, 32); }
            float mean = s * (1.f / C);
            float rstd = rsqrtf(ss * (1.f / C) - mean * mean + 1e-6f);
            float4 gg = *(const float4*)&g[l2 * 4];
            float4 bb = *(const float4*)&b[l2 * 4];
            float e0 = (v.x - mean) * rstd * gg.x + bb.x;
            float e1 = (v.y - mean) * rstd * gg.y + bb.y;
            float e2 = (v.z - mean) * rstd * gg.z + bb.z;
            float e3 = (v.w - mean) * rstd * gg.w + bb.w;
            if (MODE == 2) {
                *(float4*)&outp[(tok0 + row) * C + l2 * 4] = make_float4(e0, e1, e2, e3);
            } else {
                *(float4*)&dst[row * LS + l2 * 4] = make_float4(e0, e1, e2, e3);
                if (MODE == 0) {
                    float4 wv = *(const float4*)&wg[l2 * 4];
                    float gp = e0*wv.x + e1*wv.y + e2*wv.z + e3*wv.w;
                    #pragma unroll
                    for (int o = 16; o > 0; o >>= 1) gp += __shfl_xor(gp, o, 32);
                    if (l2 == 0) gate_s[row] = 1.f / (1.f + expf(-(gp + bgate)));
                }
            }
        }
    }
}

extern "C" __global__ __launch_bounds__(256, 1)
void pose3d_diag(const float* __restrict__ x, const float* __restrict__ adj,
                 const float* __restrict__ w_embed, const float* __restrict__ b_embed,
                 const float* __restrict__ pos,
                 const float* __restrict__ ln1_g, const float* __restrict__ ln1_b,
                 const float* __restrict__ w_qkv, const float* __restrict__ b_qkv,
                 const float* __restrict__ w_gate, const float* __restrict__ b_gate,
                 const float* __restrict__ w_proj, const float* __restrict__ b_proj,
                 const float* __restrict__ ln2_g, const float* __restrict__ ln2_b,
                 const float* __restrict__ w_fc1, const float* __restrict__ b_fc1,
                 const float* __restrict__ w_fc2, const float* __restrict__ b_fc2,
                 const float* __restrict__ fn_g, const float* __restrict__ fn_b,
                 float* __restrict__ out)
{
    __shared__ __align__(16) float h_s[ROWS * LS];            // residual fp32
    __shared__ __align__(16) float a_s[ROWS * LS];            // y / o / y2 fp32
    __shared__ __align__(16) unsigned short u_s[3 * SEGQ];    // q,k,v bf16; overlaid by t fp32
    __shared__ float adj_s[P * P];
    __shared__ float gate_s[ROWS];
    float* t_s = (float*)u_s;                                 // 34*132 fp32 fits in u_s

    const int tid = threadIdx.x;
    const int wave = tid >> 6, lane = tid & 63;
    const int blk = blockIdx.x;
    const int n128 = tid & 127, rg = tid >> 7;                // col / row-group split

    // ---- embed ----
    for (int idx = tid; idx < ROWS * C; idx += 256) {
        int row = idx >> 7, c = idx & 127;
        int s = row / 17, p = row % 17;
        int xb = (blk * SPB + s) * (P * 2) + p * 2;
        h_s[row * LS + c] = x[xb] * w_embed[c] + x[xb + 1] * w_embed[C + c]
                          + b_embed[c] + pos[p * C + c];
    }
    for (int idx = tid; idx < P * P; idx += 256) adj_s[idx] = adj[idx];
    __syncthreads();

    for (int i = 0; i < DEPTH; ++i) {
        // ---- LN1 + gate -> a_s ----
        ln_stage<0>(h_s, a_s, gate_s, ln1_g + i * C, ln1_b + i * C,
                    w_gate + i * C, b_gate[i], nullptr, 0, wave, lane);
        __syncthreads();

        // ---- qkv VALU GEMM: a_s(34x128) @ w_qkv(128x384) -> u_s bf16 ----
        for (int rep = 0; rep < 2; ++rep) {
            int n = tid + rep * 256;
            if (n < 3 * C) {
                float acc[ROWS];
                #pragma unroll
                for (int r = 0; r < ROWS; ++r) acc[r] = 0.f;
                const float* Wc = w_qkv + i * C * (3 * C) + n;
                for (int k4 = 0; k4 < C; k4 += 4) {
                    float w0 = Wc[(k4 + 0) * 384];
                    float w1 = Wc[(k4 + 1) * 384];
                    float w2 = Wc[(k4 + 2) * 384];
                    float w3 = Wc[(k4 + 3) * 384];
                    #pragma unroll
                    for (int r = 0; r < ROWS; ++r) {
                        float4 av = *(const float4*)&a_s[r * LS + k4];
                        acc[r] += av.x * w0 + av.y * w1 + av.z * w2 + av.w * w3;
                    }
                }
                float bias = b_qkv[i * 384 + n];
                int t = n >> 7, cc = n & 127;
                #pragma unroll
                for (int r = 0; r < ROWS; ++r)
                    u_s[t * SEGQ + r * QS + cc] = f2bf(acc[r] + bias);
            }
        }
        __syncthreads();

        // ---- attention fp32, q/k/v bf16; o -> a_s fp32 ----
        for (int task = tid; task < 272; task += 256) {
            int n = task >> 4, sh = task & 15;
            int s = sh >> 3, hh = sh & 7;
            int base = s * 17;
            float qv[16];
            { const uint4* qp = (const uint4*)&u_s[(base + n) * QS + hh * 16];
              unpack8(qp[0], qv); unpack8(qp[1], qv + 8); }
            float Sv[17]; float mx = -1e30f;
            #pragma unroll
            for (int mm = 0; mm < 17; ++mm) {
                const uint4* kp = (const uint4*)&u_s[SEGQ + (base + mm) * QS + hh * 16];
                float kf[16]; unpack8(kp[0], kf); unpack8(kp[1], kf + 8);
                float acc = 0.f;
                #pragma unroll
                for (int d = 0; d < 16; ++d) acc += qv[d] * kf[d];
                float gt = gate_s[base + mm];
                float aa = acc * 0.25f * (1.f - gt) + adj_s[n * P + mm] * gt;
                Sv[mm] = aa; mx = fmaxf(mx, aa);
            }
            float sum = 0.f;
            #pragma unroll
            for (int mm = 0; mm < 17; ++mm) { float e = expf(Sv[mm] - mx); Sv[mm] = e; sum += e; }
            float inv = 1.f / sum;
            float ov[16];
            #pragma unroll
            for (int d = 0; d < 16; ++d) ov[d] = 0.f;
            #pragma unroll
            for (int mm = 0; mm < 17; ++mm) {
                const uint4* vp = (const uint4*)&u_s[2 * SEGQ + (base + mm) * QS + hh * 16];
                float vf[16]; unpack8(vp[0], vf); unpack8(vp[1], vf + 8);
                float w = Sv[mm];
                #pragma unroll
                for (int d = 0; d < 16; ++d) ov[d] += w * vf[d];
            }
            float* op = &a_s[(base + n) * LS + hh * 16];
            #pragma unroll
            for (int d = 0; d < 16; ++d) op[d] = ov[d] * inv;
        }
        __syncthreads();

        // ---- proj VALU GEMM + residual: h += a_s(o) @ w_proj ----
        {
            float acc[17];
            #pragma unroll
            for (int r = 0; r < 17; ++r) acc[r] = 0.f;
            const float* Wc = w_proj + i * C * C + n128;
            for (int k4 = 0; k4 < C; k4 += 4) {
                float w0 = Wc[(k4 + 0) * 128];
                float w1 = Wc[(k4 + 1) * 128];
                float w2 = Wc[(k4 + 2) * 128];
                float w3 = Wc[(k4 + 3) * 128];
                #pragma unroll
                for (int r = 0; r < 17; ++r) {
                    float4 av = *(const float4*)&a_s[(rg * 17 + r) * LS + k4];
                    acc[r] += av.x * w0 + av.y * w1 + av.z * w2 + av.w * w3;
                }
            }
            float bias = b_proj[i * C + n128];
            #pragma unroll
            for (int r = 0; r < 17; ++r)
                h_s[(rg * 17 + r) * LS + n128] += acc[r] + bias;
        }
        __syncthreads();

        // ---- LN2 -> a_s ----
        ln_stage<1>(h_s, a_s, gate_s, ln2_g + i * C, ln2_b + i * C,
                    nullptr, 0.f, nullptr, 0, wave, lane);
        __syncthreads();

        // ---- MLP in two HID-halves; fc2 acc persists ----
        {
            float acc2[17];
            #pragma unroll
            for (int r = 0; r < 17; ++r) acc2[r] = 0.f;
            for (int hf = 0; hf < 2; ++hf) {
                float acc1[17];
                #pragma unroll
                for (int r = 0; r < 17; ++r) acc1[r] = 0.f;
                const float* Wc1 = w_fc1 + i * C * HID + hf * 128 + n128;
                for (int k4 = 0; k4 < C; k4 += 4) {
                    float w0 = Wc1[(k4 + 0) * 256];
                    float w1 = Wc1[(k4 + 1) * 256];
                    float w2 = Wc1[(k4 + 2) * 256];
                    float w3 = Wc1[(k4 + 3) * 256];
                    #pragma unroll
                    for (int r = 0; r < 17; ++r) {
                        float4 av = *(const float4*)&a_s[(rg * 17 + r) * LS + k4];
                        acc1[r] += av.x * w0 + av.y * w1 + av.z * w2 + av.w * w3;
                    }
                }
                float b1v = b_fc1[i * HID + hf * 128 + n128];
                #pragma unroll
                for (int r = 0; r < 17; ++r) {
                    float uu = acc1[r] + b1v;
                    t_s[(rg * 17 + r) * LS + n128] =
                        0.5f * uu * (1.f + erff(uu * 0.70710678118654752f));
                }
                __syncthreads();
                const float* Wc2 = w_fc2 + i * HID * C + (hf * 128) * C + n128;
                for (int k4 = 0; k4 < C; k4 += 4) {
                    float w0 = Wc2[(k4 + 0) * 128];
                    float w1 = Wc2[(k4 + 1) * 128];
                    float w2 = Wc2[(k4 + 2) * 128];
                    float w3 = Wc2[(k4 + 3) * 128];
                    #pragma unroll
                    for (int r = 0; r < 17; ++r) {
                        float4 av = *(const float4*)&t_s[(rg * 17 + r) * LS + k4];
                        acc2[r] += av.x * w0 + av.y * w1 + av.z * w2 + av.w * w3;
                    }
                }
                __syncthreads();
            }
            float b2v = b_fc2[i * C + n128];
            #pragma unroll
            for (int r = 0; r < 17; ++r)
                h_s[(rg * 17 + r) * LS + n128] += acc2[r] + b2v;
        }
        __syncthreads();
    }

    // ---- final LN -> out ----
    ln_stage<2>(h_s, nullptr, nullptr, fn_g, fn_b, nullptr, 0.f, out, blk * ROWS, wave, lane);
}

extern "C" void kernel_launch(void* const* d_in, const int* in_sizes, int n_in,
                              void* d_out, int out_size, void* d_ws, size_t ws_size,
                              hipStream_t stream) {
    const float* x       = (const float*)d_in[0];
    const float* adj     = (const float*)d_in[1];
    const float* w_embed = (const float*)d_in[2];
    const float* b_embed = (const float*)d_in[3];
    const float* pos     = (const float*)d_in[4];
    const float* ln1_g   = (const float*)d_in[5];
    const float* ln1_b   = (const float*)d_in[6];
    const float* w_qkv   = (const float*)d_in[7];
    const float* b_qkv   = (const float*)d_in[8];
    const float* w_gate  = (const float*)d_in[9];
    const float* b_gate  = (const float*)d_in[10];
    const float* w_proj  = (const float*)d_in[11];
    const float* b_proj  = (const float*)d_in[12];
    const float* ln2_g   = (const float*)d_in[13];
    const float* ln2_b   = (const float*)d_in[14];
    const float* w_fc1   = (const float*)d_in[15];
    const float* b_fc1   = (const float*)d_in[16];
    const float* w_fc2   = (const float*)d_in[17];
    const float* b_fc2   = (const float*)d_in[18];
    const float* fn_g    = (const float*)d_in[19];
    const float* fn_b    = (const float*)d_in[20];
    float* out = (float*)d_out;

    pose3d_diag<<<3888, 256, 0, stream>>>(x, adj, w_embed, b_embed, pos,
        ln1_g, ln1_b, w_qkv, b_qkv, w_gate, b_gate, w_proj, b_proj,
        ln2_g, ln2_b, w_fc1, b_fc1, w_fc2, b_fc2, fn_g, fn_b, out);
}

// Round 6
// 5894.126 us; speedup vs baseline: 1.2940x; 1.2940x over previous
//
#include <hip/hip_runtime.h>
#include <math.h>

#define DEPTH 4
#define C 128
#define P 17
#define HID 256
#define SPB 2
#define ROWS 34          // SPB*P
#define MT 3             // M tiles (48 rows padded)
#define LS 132           // fp32 LDS row stride
#define QS 136           // bf16 q/k/v row stride
#define SEGQ (ROWS*QS)   // 4624
#define AS 264           // hi/lo bf16 row stride (128 hi | 128 lo | 8 pad)
#define OFFT 8976        // t region inside arena (34*AS)
#define ARENA_N 22000    // covers garbage A-row reads up to row 47

// workspace: W^T planes, row-major N x K, bf16. hi plane [0,524288), lo at +524288.
#define WTQ 0
#define WTP 196608
#define WT1 262144
#define WT2 393216
#define LO_OFF 524288

typedef short short8 __attribute__((ext_vector_type(8)));
typedef float f32x4 __attribute__((ext_vector_type(4)));

__device__ __forceinline__ unsigned short f2bf(float f) {
    unsigned int u = __float_as_uint(f);
    u += 0x7FFFu + ((u >> 16) & 1u);
    return (unsigned short)(u >> 16);
}
__device__ __forceinline__ float bf2f(unsigned short s) {
    return __uint_as_float((unsigned int)s << 16);
}
__device__ __forceinline__ void unpack8(uint4 u, float* f) {
    f[0] = __uint_as_float(u.x << 16); f[1] = __uint_as_float(u.x & 0xffff0000u);
    f[2] = __uint_as_float(u.y << 16); f[3] = __uint_as_float(u.y & 0xffff0000u);
    f[4] = __uint_as_float(u.z << 16); f[5] = __uint_as_float(u.z & 0xffff0000u);
    f[6] = __uint_as_float(u.w << 16); f[7] = __uint_as_float(u.w & 0xffff0000u);
}

// ---------------- prep: transpose W (KxN) -> WT (NxK row-major), hi+lo ----------------
extern "C" __global__ void prep_wt(const float* __restrict__ wq, const float* __restrict__ wp,
                                   const float* __restrict__ w1, const float* __restrict__ w2,
                                   unsigned short* __restrict__ ws) {
    int idx = blockIdx.x * 256 + threadIdx.x;   // grid 2048*256 = 524288 exactly
    int rel = idx; const float* W; int K, N;
    if (rel < 196608)                  { W = wq; K = 128; N = 384; }
    else if ((rel -= 196608) < 65536)  { W = wp; K = 128; N = 128; }
    else if ((rel -= 65536) < 131072)  { W = w1; K = 128; N = 256; }
    else { rel -= 131072;                W = w2; K = 256; N = 128; }
    int per = K * N;
    int l = rel / per, r = rel % per;
    int n = r / K, k = r % K;          // WT[n][k], k fastest
    float wv = W[l * per + k * N + n];
    unsigned short h = f2bf(wv);
    ws[idx] = h;
    ws[idx + LO_OFF] = f2bf(wv - bf2f(h));
}

// ---------------- MFMA GEMM, symmetric A.B^T pattern (round-5 transplant) ----------------
template<int NTW, int KS>
__device__ __forceinline__ void gemm_bt(const unsigned short* A, int astride, int aLoOff,
        const unsigned short* __restrict__ WT, int ldk, int ntoff, int ksoff,
        int wave, int lane, f32x4 (&acc)[MT][NTW])
{
    int m = lane & 15, q = lane >> 4;
    for (int ks = 0; ks < KS; ++ks) {
        short8 ah[MT], al[MT];
        #pragma unroll
        for (int mt = 0; mt < MT; ++mt) {
            ah[mt] = *(const short8*)&A[(mt * 16 + m) * astride + ks * 32 + q * 8];
            al[mt] = *(const short8*)&A[(mt * 16 + m) * astride + aLoOff + ks * 32 + q * 8];
        }
        #pragma unroll
        for (int nt = 0; nt < NTW; ++nt) {
            int nrow = (ntoff + wave * NTW + nt) * 16 + m;
            const unsigned short* bp = WT + nrow * ldk + (ksoff + ks) * 32 + q * 8;
            short8 bh = *(const short8*)bp;
            short8 bl = *(const short8*)(bp + LO_OFF);
            #pragma unroll
            for (int mt = 0; mt < MT; ++mt) {
                acc[mt][nt] = __builtin_amdgcn_mfma_f32_16x16x32_bf16(ah[mt], bh, acc[mt][nt], 0, 0, 0);
                acc[mt][nt] = __builtin_amdgcn_mfma_f32_16x16x32_bf16(al[mt], bh, acc[mt][nt], 0, 0, 0);
                acc[mt][nt] = __builtin_amdgcn_mfma_f32_16x16x32_bf16(ah[mt], bl, acc[mt][nt], 0, 0, 0);
            }
        }
    }
}

template<int NTW>
__device__ __forceinline__ void zero_acc(f32x4 (&acc)[MT][NTW]) {
    #pragma unroll
    for (int mt = 0; mt < MT; ++mt)
        #pragma unroll
        for (int nt = 0; nt < NTW; ++nt) acc[mt][nt] = (f32x4){0.f, 0.f, 0.f, 0.f};
}

// MODE 0 = ln1 (+gate), 1 = ln2, 2 = final->out. fp32 everywhere.
template<int MODE>
__device__ __forceinline__ void ln_stage(const float* h_s, float* dst, float* gate_s,
        const float* __restrict__ g, const float* __restrict__ b,
        const float* __restrict__ wg, float bgate,
        float* __restrict__ outp, int tok0, int wave, int lane)
{
    int half = lane >> 5, l2 = lane & 31;
    #pragma unroll
    for (int it = 0; it < 5; ++it) {
        int row = it * 8 + wave * 2 + half;   // 0..39, each once
        if (row < ROWS) {
            float4 v = *(const float4*)&h_s[row * LS + l2 * 4];
            float s  = v.x + v.y + v.z + v.w;
            float ss = v.x*v.x + v.y*v.y + v.z*v.z + v.w*v.w;
            #pragma unroll
            for (int o = 16; o > 0; o >>= 1) { s += __shfl_xor(s, o, 32); ss += __shfl_xor(ss, o, 32); }
            float mean = s * (1.f / C);
            float rstd = rsqrtf(ss * (1.f / C) - mean * mean + 1e-6f);
            float4 gg = *(const float4*)&g[l2 * 4];
            float4 bb = *(const float4*)&b[l2 * 4];
            float e0 = (v.x - mean) * rstd * gg.x + bb.x;
            float e1 = (v.y - mean) * rstd * gg.y + bb.y;
            float e2 = (v.z - mean) * rstd * gg.z + bb.z;
            float e3 = (v.w - mean) * rstd * gg.w + bb.w;
            if (MODE == 2) {
                *(float4*)&outp[(tok0 + row) * C + l2 * 4] = make_float4(e0, e1, e2, e3);
            } else {
                *(float4*)&dst[row * LS + l2 * 4] = make_float4(e0, e1, e2, e3);
                if (MODE == 0) {
                    float4 wv = *(const float4*)&wg[l2 * 4];
                    float gp = e0*wv.x + e1*wv.y + e2*wv.z + e3*wv.w;
                    #pragma unroll
                    for (int o = 16; o > 0; o >>= 1) gp += __shfl_xor(gp, o, 32);
                    if (l2 == 0) gate_s[row] = 1.f / (1.f + expf(-(gp + bgate)));
                }
            }
        }
    }
}

extern "C" __global__ __launch_bounds__(256, 1)
void pose3d_bisect(const float* __restrict__ x, const float* __restrict__ adj,
                 const float* __restrict__ w_embed, const float* __restrict__ b_embed,
                 const float* __restrict__ pos,
                 const float* __restrict__ ln1_g, const float* __restrict__ ln1_b,
                 const float* __restrict__ w_qkv, const float* __restrict__ b_qkv,
                 const float* __restrict__ w_gate, const float* __restrict__ b_gate,
                 const float* __restrict__ w_proj, const float* __restrict__ b_proj,
                 const float* __restrict__ ln2_g, const float* __restrict__ ln2_b,
                 const float* __restrict__ b_fc1, const float* __restrict__ b_fc2,
                 const float* __restrict__ fn_g, const float* __restrict__ fn_b,
                 const unsigned short* __restrict__ wsw,
                 float* __restrict__ out)
{
    __shared__ __align__(16) float h_s[ROWS * LS];            // residual fp32
    __shared__ __align__(16) float a_s[ROWS * LS];            // y / o / y2 fp32
    __shared__ __align__(16) unsigned short u_s[3 * SEGQ];    // q,k,v bf16
    __shared__ __align__(16) unsigned short arena[ARENA_N];   // MLP hi/lo: y2 at 0, t at OFFT
    __shared__ float adj_s[P * P];
    __shared__ float gate_s[ROWS];

    const int tid = threadIdx.x;
    const int wave = tid >> 6, lane = tid & 63;
    const int m16 = lane & 15, q4 = lane >> 4;
    const int blk = blockIdx.x;
    const int n128 = tid & 127, rg = tid >> 7;

    // ---- embed ----
    for (int idx = tid; idx < ROWS * C; idx += 256) {
        int row = idx >> 7, c = idx & 127;
        int s = row / 17, p = row % 17;
        int xb = (blk * SPB + s) * (P * 2) + p * 2;
        h_s[row * LS + c] = x[xb] * w_embed[c] + x[xb + 1] * w_embed[C + c]
                          + b_embed[c] + pos[p * C + c];
    }
    for (int idx = tid; idx < P * P; idx += 256) adj_s[idx] = adj[idx];
    __syncthreads();

    for (int i = 0; i < DEPTH; ++i) {
        // ---- LN1 + gate -> a_s (VALU, proven) ----
        ln_stage<0>(h_s, a_s, gate_s, ln1_g + i * C, ln1_b + i * C,
                    w_gate + i * C, b_gate[i], nullptr, 0, wave, lane);
        __syncthreads();

        // ---- qkv VALU GEMM (proven) ----
        for (int rep = 0; rep < 2; ++rep) {
            int n = tid + rep * 256;
            if (n < 3 * C) {
                float acc[ROWS];
                #pragma unroll
                for (int r = 0; r < ROWS; ++r) acc[r] = 0.f;
                const float* Wc = w_qkv + i * C * (3 * C) + n;
                for (int k4 = 0; k4 < C; k4 += 4) {
                    float w0 = Wc[(k4 + 0) * 384];
                    float w1 = Wc[(k4 + 1) * 384];
                    float w2 = Wc[(k4 + 2) * 384];
                    float w3 = Wc[(k4 + 3) * 384];
                    #pragma unroll
                    for (int r = 0; r < ROWS; ++r) {
                        float4 av = *(const float4*)&a_s[r * LS + k4];
                        acc[r] += av.x * w0 + av.y * w1 + av.z * w2 + av.w * w3;
                    }
                }
                float bias = b_qkv[i * 384 + n];
                int t = n >> 7, cc = n & 127;
                #pragma unroll
                for (int r = 0; r < ROWS; ++r)
                    u_s[t * SEGQ + r * QS + cc] = f2bf(acc[r] + bias);
            }
        }
        __syncthreads();

        // ---- attention (proven) ----
        for (int task = tid; task < 272; task += 256) {
            int n = task >> 4, sh = task & 15;
            int s = sh >> 3, hh = sh & 7;
            int base = s * 17;
            float qv[16];
            { const uint4* qp = (const uint4*)&u_s[(base + n) * QS + hh * 16];
              unpack8(qp[0], qv); unpack8(qp[1], qv + 8); }
            float Sv[17]; float mx = -1e30f;
            #pragma unroll
            for (int mm = 0; mm < 17; ++mm) {
                const uint4* kp = (const uint4*)&u_s[SEGQ + (base + mm) * QS + hh * 16];
                float kf[16]; unpack8(kp[0], kf); unpack8(kp[1], kf + 8);
                float acc = 0.f;
                #pragma unroll
                for (int d = 0; d < 16; ++d) acc += qv[d] * kf[d];
                float gt = gate_s[base + mm];
                float aa = acc * 0.25f * (1.f - gt) + adj_s[n * P + mm] * gt;
                Sv[mm] = aa; mx = fmaxf(mx, aa);
            }
            float sum = 0.f;
            #pragma unroll
            for (int mm = 0; mm < 17; ++mm) { float e = expf(Sv[mm] - mx); Sv[mm] = e; sum += e; }
            float inv = 1.f / sum;
            float ov[16];
            #pragma unroll
            for (int d = 0; d < 16; ++d) ov[d] = 0.f;
            #pragma unroll
            for (int mm = 0; mm < 17; ++mm) {
                const uint4* vp = (const uint4*)&u_s[2 * SEGQ + (base + mm) * QS + hh * 16];
                float vf[16]; unpack8(vp[0], vf); unpack8(vp[1], vf + 8);
                float w = Sv[mm];
                #pragma unroll
                for (int d = 0; d < 16; ++d) ov[d] += w * vf[d];
            }
            float* op = &a_s[(base + n) * LS + hh * 16];
            #pragma unroll
            for (int d = 0; d < 16; ++d) op[d] = ov[d] * inv;
        }
        __syncthreads();

        // ---- proj VALU GEMM + residual (proven) ----
        {
            float acc[17];
            #pragma unroll
            for (int r = 0; r < 17; ++r) acc[r] = 0.f;
            const float* Wc = w_proj + i * C * C + n128;
            for (int k4 = 0; k4 < C; k4 += 4) {
                float w0 = Wc[(k4 + 0) * 128];
                float w1 = Wc[(k4 + 1) * 128];
                float w2 = Wc[(k4 + 2) * 128];
                float w3 = Wc[(k4 + 3) * 128];
                #pragma unroll
                for (int r = 0; r < 17; ++r) {
                    float4 av = *(const float4*)&a_s[(rg * 17 + r) * LS + k4];
                    acc[r] += av.x * w0 + av.y * w1 + av.z * w2 + av.w * w3;
                }
            }
            float bias = b_proj[i * C + n128];
            #pragma unroll
            for (int r = 0; r < 17; ++r)
                h_s[(rg * 17 + r) * LS + n128] += acc[r] + bias;
        }
        __syncthreads();

        // ---- LN2 -> a_s (VALU, proven) ----
        ln_stage<1>(h_s, a_s, gate_s, ln2_g + i * C, ln2_b + i * C,
                    nullptr, 0.f, nullptr, 0, wave, lane);
        __syncthreads();

        // ==== MLP via MFMA — THE TEST SUBJECT (round-5 transplant) ====
        // stage y2 fp32 -> arena hi/lo
        for (int idx = tid; idx < ROWS * C; idx += 256) {
            int row = idx >> 7, c = idx & 127;
            float e = a_s[row * LS + c];
            unsigned short hb = f2bf(e);
            arena[row * AS + c] = hb;
            arena[row * AS + 128 + c] = f2bf(e - bf2f(hb));
        }
        __syncthreads();
        {
            f32x4 acc2[MT][2];
            zero_acc<2>(acc2);
            for (int hf = 0; hf < 2; ++hf) {
                f32x4 acc1[MT][2];
                zero_acc<2>(acc1);
                gemm_bt<2, 4>(arena, AS, 128, wsw + WT1 + i * 32768, 128, hf * 8, 0, wave, lane, acc1);
                const float* b1 = b_fc1 + i * HID + hf * 128;
                #pragma unroll
                for (int nt = 0; nt < 2; ++nt) {
                    int nl = (wave * 2 + nt) * 16 + m16;
                    float bias = b1[nl];
                    #pragma unroll
                    for (int mt = 0; mt < MT; ++mt)
                        #pragma unroll
                        for (int r = 0; r < 4; ++r) {
                            int row = mt * 16 + q4 * 4 + r;
                            if (row < ROWS) {
                                float xx = acc1[mt][nt][r] + bias;
                                float ge = 0.5f * xx * (1.f + erff(xx * 0.70710678118654752f));
                                unsigned short hb = f2bf(ge);
                                arena[OFFT + row * AS + nl] = hb;
                                arena[OFFT + row * AS + 128 + nl] = f2bf(ge - bf2f(hb));
                            }
                        }
                }
                __syncthreads();   // t half visible
                gemm_bt<2, 4>(arena + OFFT, AS, 128, wsw + WT2 + i * 32768, 256, 0, hf * 4, wave, lane, acc2);
                __syncthreads();   // done reading t before next half overwrites
            }
            const float* b2 = b_fc2 + i * C;
            #pragma unroll
            for (int nt = 0; nt < 2; ++nt) {
                int n = (wave * 2 + nt) * 16 + m16;
                float bias = b2[n];
                #pragma unroll
                for (int mt = 0; mt < MT; ++mt)
                    #pragma unroll
                    for (int r = 0; r < 4; ++r) {
                        int row = mt * 16 + q4 * 4 + r;
                        if (row < ROWS) h_s[row * LS + n] += acc2[mt][nt][r] + bias;
                    }
            }
        }
        __syncthreads();
    }

    // ---- final LN -> out ----
    ln_stage<2>(h_s, nullptr, nullptr, fn_g, fn_b, nullptr, 0.f, out, blk * ROWS, wave, lane);
}

extern "C" void kernel_launch(void* const* d_in, const int* in_sizes, int n_in,
                              void* d_out, int out_size, void* d_ws, size_t ws_size,
                              hipStream_t stream) {
    const float* x       = (const float*)d_in[0];
    const float* adj     = (const float*)d_in[1];
    const float* w_embed = (const float*)d_in[2];
    const float* b_embed = (const float*)d_in[3];
    const float* pos     = (const float*)d_in[4];
    const float* ln1_g   = (const float*)d_in[5];
    const float* ln1_b   = (const float*)d_in[6];
    const float* w_qkv   = (const float*)d_in[7];
    const float* b_qkv   = (const float*)d_in[8];
    const float* w_gate  = (const float*)d_in[9];
    const float* b_gate  = (const float*)d_in[10];
    const float* w_proj  = (const float*)d_in[11];
    const float* b_proj  = (const float*)d_in[12];
    const float* ln2_g   = (const float*)d_in[13];
    const float* ln2_b   = (const float*)d_in[14];
    const float* w_fc1   = (const float*)d_in[15];
    const float* b_fc1   = (const float*)d_in[16];
    const float* w_fc2   = (const float*)d_in[17];
    const float* b_fc2   = (const float*)d_in[18];
    const float* fn_g    = (const float*)d_in[19];
    const float* fn_b    = (const float*)d_in[20];
    unsigned short* ws   = (unsigned short*)d_ws;   // 2 MiB
    float* out = (float*)d_out;

    prep_wt<<<2048, 256, 0, stream>>>(w_qkv, w_proj, w_fc1, w_fc2, ws);
    pose3d_bisect<<<3888, 256, 0, stream>>>(x, adj, w_embed, b_embed, pos,
        ln1_g, ln1_b, w_qkv, b_qkv, w_gate, b_gate, w_proj, b_proj,
        ln2_g, ln2_b, b_fc1, b_fc2, fn_g, fn_b, ws, out);
}

// Round 7
// 2423.855 us; speedup vs baseline: 3.1467x; 2.4317x over previous
//
#include <hip/hip_runtime.h>
#include <math.h>

#define DEPTH 4
#define C 128
#define P 17
#define HID 256
#define SPB 2
#define ROWS 34          // SPB*P
#define MT 3             // M tiles (48 rows padded)
#define LS 132           // fp32 LDS row stride
#define QS 136           // bf16 q/k/v row stride
#define SEGQ (ROWS*QS)   // 4624
#define AS 264           // hi/lo bf16 row stride (128 hi | 128 lo | 8 pad)
#define OFFT 8976        // t region inside arena (34*AS)
#define ARENA_N 22000    // covers garbage A-row reads up to row 47

// workspace: W^T planes, row-major N x K, bf16. hi plane [0,524288), lo at +524288.
#define WTQ 0
#define WTP 196608
#define WT1 262144
#define WT2 393216
#define LO_OFF 524288

typedef short short8 __attribute__((ext_vector_type(8)));
typedef float f32x4 __attribute__((ext_vector_type(4)));

__device__ __forceinline__ unsigned short f2bf(float f) {
    unsigned int u = __float_as_uint(f);
    u += 0x7FFFu + ((u >> 16) & 1u);
    return (unsigned short)(u >> 16);
}
__device__ __forceinline__ float bf2f(unsigned short s) {
    return __uint_as_float((unsigned int)s << 16);
}
__device__ __forceinline__ void unpack8(uint4 u, float* f) {
    f[0] = __uint_as_float(u.x << 16); f[1] = __uint_as_float(u.x & 0xffff0000u);
    f[2] = __uint_as_float(u.y << 16); f[3] = __uint_as_float(u.y & 0xffff0000u);
    f[4] = __uint_as_float(u.z << 16); f[5] = __uint_as_float(u.z & 0xffff0000u);
    f[6] = __uint_as_float(u.w << 16); f[7] = __uint_as_float(u.w & 0xffff0000u);
}

// ---------------- prep: transpose W (KxN) -> WT (NxK row-major), hi+lo ----------------
extern "C" __global__ void prep_wt(const float* __restrict__ wq, const float* __restrict__ wp,
                                   const float* __restrict__ w1, const float* __restrict__ w2,
                                   unsigned short* __restrict__ ws) {
    int idx = blockIdx.x * 256 + threadIdx.x;   // grid 2048*256 = 524288 exactly
    int rel = idx; const float* W; int K, N;
    if (rel < 196608)                  { W = wq; K = 128; N = 384; }
    else if ((rel -= 196608) < 65536)  { W = wp; K = 128; N = 128; }
    else if ((rel -= 65536) < 131072)  { W = w1; K = 128; N = 256; }
    else { rel -= 131072;                W = w2; K = 256; N = 128; }
    int per = K * N;
    int l = rel / per, r = rel % per;
    int n = r / K, k = r % K;          // WT[n][k], k fastest
    float wv = W[l * per + k * N + n];
    unsigned short h = f2bf(wv);
    ws[idx] = h;
    ws[idx + LO_OFF] = f2bf(wv - bf2f(h));
}

// ---------------- MFMA GEMM, symmetric A.B^T pattern (PROVEN round 6) ----------------
template<int NTW, int KS>
__device__ __forceinline__ void gemm_bt(const unsigned short* A, int astride, int aLoOff,
        const unsigned short* __restrict__ WT, int ldk, int ntoff, int ksoff,
        int wave, int lane, f32x4 (&acc)[MT][NTW])
{
    int m = lane & 15, q = lane >> 4;
    for (int ks = 0; ks < KS; ++ks) {
        short8 ah[MT], al[MT];
        #pragma unroll
        for (int mt = 0; mt < MT; ++mt) {
            ah[mt] = *(const short8*)&A[(mt * 16 + m) * astride + ks * 32 + q * 8];
            al[mt] = *(const short8*)&A[(mt * 16 + m) * astride + aLoOff + ks * 32 + q * 8];
        }
        #pragma unroll
        for (int nt = 0; nt < NTW; ++nt) {
            int nrow = (ntoff + wave * NTW + nt) * 16 + m;
            const unsigned short* bp = WT + nrow * ldk + (ksoff + ks) * 32 + q * 8;
            short8 bh = *(const short8*)bp;
            short8 bl = *(const short8*)(bp + LO_OFF);
            #pragma unroll
            for (int mt = 0; mt < MT; ++mt) {
                acc[mt][nt] = __builtin_amdgcn_mfma_f32_16x16x32_bf16(ah[mt], bh, acc[mt][nt], 0, 0, 0);
                acc[mt][nt] = __builtin_amdgcn_mfma_f32_16x16x32_bf16(al[mt], bh, acc[mt][nt], 0, 0, 0);
                acc[mt][nt] = __builtin_amdgcn_mfma_f32_16x16x32_bf16(ah[mt], bl, acc[mt][nt], 0, 0, 0);
            }
        }
    }
}

template<int NTW>
__device__ __forceinline__ void zero_acc(f32x4 (&acc)[MT][NTW]) {
    #pragma unroll
    for (int mt = 0; mt < MT; ++mt)
        #pragma unroll
        for (int nt = 0; nt < NTW; ++nt) acc[mt][nt] = (f32x4){0.f, 0.f, 0.f, 0.f};
}

// MODE 0 = ln1 (+gate), 1 = ln2, 2 = final->out. fp32 everywhere (PROVEN).
template<int MODE>
__device__ __forceinline__ void ln_stage(const float* h_s, float* dst, float* gate_s,
        const float* __restrict__ g, const float* __restrict__ b,
        const float* __restrict__ wg, float bgate,
        float* __restrict__ outp, int tok0, int wave, int lane)
{
    int half = lane >> 5, l2 = lane & 31;
    #pragma unroll
    for (int it = 0; it < 5; ++it) {
        int row = it * 8 + wave * 2 + half;   // 0..39, each once
        if (row < ROWS) {
            float4 v = *(const float4*)&h_s[row * LS + l2 * 4];
            float s  = v.x + v.y + v.z + v.w;
            float ss = v.x*v.x + v.y*v.y + v.z*v.z + v.w*v.w;
            #pragma unroll
            for (int o = 16; o > 0; o >>= 1) { s += __shfl_xor(s, o, 32); ss += __shfl_xor(ss, o, 32); }
            float mean = s * (1.f / C);
            float rstd = rsqrtf(ss * (1.f / C) - mean * mean + 1e-6f);
            float4 gg = *(const float4*)&g[l2 * 4];
            float4 bb = *(const float4*)&b[l2 * 4];
            float e0 = (v.x - mean) * rstd * gg.x + bb.x;
            float e1 = (v.y - mean) * rstd * gg.y + bb.y;
            float e2 = (v.z - mean) * rstd * gg.z + bb.z;
            float e3 = (v.w - mean) * rstd * gg.w + bb.w;
            if (MODE == 2) {
                *(float4*)&outp[(tok0 + row) * C + l2 * 4] = make_float4(e0, e1, e2, e3);
            } else {
                *(float4*)&dst[row * LS + l2 * 4] = make_float4(e0, e1, e2, e3);
                if (MODE == 0) {
                    float4 wv = *(const float4*)&wg[l2 * 4];
                    float gp = e0*wv.x + e1*wv.y + e2*wv.z + e3*wv.w;
                    #pragma unroll
                    for (int o = 16; o > 0; o >>= 1) gp += __shfl_xor(gp, o, 32);
                    if (l2 == 0) gate_s[row] = 1.f / (1.f + expf(-(gp + bgate)));
                }
            }
        }
    }
}

extern "C" __global__ __launch_bounds__(256, 1)
void pose3d_r7(const float* __restrict__ x, const float* __restrict__ adj,
                 const float* __restrict__ w_embed, const float* __restrict__ b_embed,
                 const float* __restrict__ pos,
                 const float* __restrict__ ln1_g, const float* __restrict__ ln1_b,
                 const float* __restrict__ b_qkv,
                 const float* __restrict__ w_gate, const float* __restrict__ b_gate,
                 const float* __restrict__ b_proj,
                 const float* __restrict__ ln2_g, const float* __restrict__ ln2_b,
                 const float* __restrict__ b_fc1, const float* __restrict__ b_fc2,
                 const float* __restrict__ fn_g, const float* __restrict__ fn_b,
                 const unsigned short* __restrict__ wsw,
                 float* __restrict__ out)
{
    __shared__ __align__(16) float h_s[ROWS * LS];            // residual fp32
    __shared__ __align__(16) float a_s[ROWS * LS];            // y / o / y2 fp32
    __shared__ __align__(16) unsigned short u_s[3 * SEGQ];    // q,k,v bf16
    __shared__ __align__(16) unsigned short arena[ARENA_N];   // hi/lo A-operands; t at OFFT
    __shared__ float adj_s[P * P];
    __shared__ float gate_s[ROWS];

    const int tid = threadIdx.x;
    const int wave = tid >> 6, lane = tid & 63;
    const int m16 = lane & 15, q4 = lane >> 4;
    const int blk = blockIdx.x;

    // ---- embed ----
    for (int idx = tid; idx < ROWS * C; idx += 256) {
        int row = idx >> 7, c = idx & 127;
        int s = row / 17, p = row % 17;
        int xb = (blk * SPB + s) * (P * 2) + p * 2;
        h_s[row * LS + c] = x[xb] * w_embed[c] + x[xb + 1] * w_embed[C + c]
                          + b_embed[c] + pos[p * C + c];
    }
    for (int idx = tid; idx < P * P; idx += 256) adj_s[idx] = adj[idx];
    __syncthreads();

    for (int i = 0; i < DEPTH; ++i) {
        // ---- LN1 + gate -> a_s fp32 (proven) ----
        ln_stage<0>(h_s, a_s, gate_s, ln1_g + i * C, ln1_b + i * C,
                    w_gate + i * C, b_gate[i], nullptr, 0, wave, lane);
        __syncthreads();

        // ---- stage y: a_s -> arena hi/lo (proven pattern) ----
        for (int idx = tid; idx < ROWS * C; idx += 256) {
            int row = idx >> 7, c = idx & 127;
            float e = a_s[row * LS + c];
            unsigned short hb = f2bf(e);
            arena[row * AS + c] = hb;
            arena[row * AS + 128 + c] = f2bf(e - bf2f(hb));
        }
        __syncthreads();

        // ---- qkv MFMA GEMM -> scatter to u_s (separate buffer, no overlap) ----
        {
            f32x4 acc[MT][6];
            zero_acc<6>(acc);
            gemm_bt<6, 4>(arena, AS, 128, wsw + WTQ + i * 49152, 128, 0, 0, wave, lane, acc);
            const float* bq = b_qkv + i * 384;
            #pragma unroll
            for (int nt = 0; nt < 6; ++nt) {
                int n = (wave * 6 + nt) * 16 + m16;
                float bias = bq[n];
                int t = n >> 7, cc = n & 127;
                #pragma unroll
                for (int mt = 0; mt < MT; ++mt)
                    #pragma unroll
                    for (int r = 0; r < 4; ++r) {
                        int row = mt * 16 + q4 * 4 + r;
                        if (row < ROWS) u_s[t * SEGQ + row * QS + cc] = f2bf(acc[mt][nt][r] + bias);
                    }
            }
        }
        __syncthreads();

        // ---- attention (VALU, proven; o -> a_s fp32) ----
        for (int task = tid; task < 272; task += 256) {
            int n = task >> 4, sh = task & 15;
            int s = sh >> 3, hh = sh & 7;
            int base = s * 17;
            float qv[16];
            { const uint4* qp = (const uint4*)&u_s[(base + n) * QS + hh * 16];
              unpack8(qp[0], qv); unpack8(qp[1], qv + 8); }
            float Sv[17]; float mx = -1e30f;
            #pragma unroll
            for (int mm = 0; mm < 17; ++mm) {
                const uint4* kp = (const uint4*)&u_s[SEGQ + (base + mm) * QS + hh * 16];
                float kf[16]; unpack8(kp[0], kf); unpack8(kp[1], kf + 8);
                float acc = 0.f;
                #pragma unroll
                for (int d = 0; d < 16; ++d) acc += qv[d] * kf[d];
                float gt = gate_s[base + mm];
                float aa = acc * 0.25f * (1.f - gt) + adj_s[n * P + mm] * gt;
                Sv[mm] = aa; mx = fmaxf(mx, aa);
            }
            float sum = 0.f;
            #pragma unroll
            for (int mm = 0; mm < 17; ++mm) { float e = expf(Sv[mm] - mx); Sv[mm] = e; sum += e; }
            float inv = 1.f / sum;
            float ov[16];
            #pragma unroll
            for (int d = 0; d < 16; ++d) ov[d] = 0.f;
            #pragma unroll
            for (int mm = 0; mm < 17; ++mm) {
                const uint4* vp = (const uint4*)&u_s[2 * SEGQ + (base + mm) * QS + hh * 16];
                float vf[16]; unpack8(vp[0], vf); unpack8(vp[1], vf + 8);
                float w = Sv[mm];
                #pragma unroll
                for (int d = 0; d < 16; ++d) ov[d] += w * vf[d];
            }
            float* op = &a_s[(base + n) * LS + hh * 16];
            #pragma unroll
            for (int d = 0; d < 16; ++d) op[d] = ov[d] * inv;
        }
        __syncthreads();

        // ---- stage o: a_s -> arena hi/lo ----
        for (int idx = tid; idx < ROWS * C; idx += 256) {
            int row = idx >> 7, c = idx & 127;
            float e = a_s[row * LS + c];
            unsigned short hb = f2bf(e);
            arena[row * AS + c] = hb;
            arena[row * AS + 128 + c] = f2bf(e - bf2f(hb));
        }
        __syncthreads();

        // ---- proj MFMA GEMM + residual into h_s (proven pattern) ----
        {
            f32x4 acc[MT][2];
            zero_acc<2>(acc);
            gemm_bt<2, 4>(arena, AS, 128, wsw + WTP + i * 16384, 128, 0, 0, wave, lane, acc);
            const float* bp = b_proj + i * C;
            #pragma unroll
            for (int nt = 0; nt < 2; ++nt) {
                int n = (wave * 2 + nt) * 16 + m16;
                float bias = bp[n];
                #pragma unroll
                for (int mt = 0; mt < MT; ++mt)
                    #pragma unroll
                    for (int r = 0; r < 4; ++r) {
                        int row = mt * 16 + q4 * 4 + r;
                        if (row < ROWS) h_s[row * LS + n] += acc[mt][nt][r] + bias;
                    }
            }
        }
        __syncthreads();

        // ---- LN2 -> a_s fp32 (proven) ----
        ln_stage<1>(h_s, a_s, gate_s, ln2_g + i * C, ln2_b + i * C,
                    nullptr, 0.f, nullptr, 0, wave, lane);
        __syncthreads();

        // ---- stage y2: a_s -> arena hi/lo ----
        for (int idx = tid; idx < ROWS * C; idx += 256) {
            int row = idx >> 7, c = idx & 127;
            float e = a_s[row * LS + c];
            unsigned short hb = f2bf(e);
            arena[row * AS + c] = hb;
            arena[row * AS + 128 + c] = f2bf(e - bf2f(hb));
        }
        __syncthreads();

        // ---- MLP via MFMA (proven round 6) ----
        {
            f32x4 acc2[MT][2];
            zero_acc<2>(acc2);
            for (int hf = 0; hf < 2; ++hf) {
                f32x4 acc1[MT][2];
                zero_acc<2>(acc1);
                gemm_bt<2, 4>(arena, AS, 128, wsw + WT1 + i * 32768, 128, hf * 8, 0, wave, lane, acc1);
                const float* b1 = b_fc1 + i * HID + hf * 128;
                #pragma unroll
                for (int nt = 0; nt < 2; ++nt) {
                    int nl = (wave * 2 + nt) * 16 + m16;
                    float bias = b1[nl];
                    #pragma unroll
                    for (int mt = 0; mt < MT; ++mt)
                        #pragma unroll
                        for (int r = 0; r < 4; ++r) {
                            int row = mt * 16 + q4 * 4 + r;
                            if (row < ROWS) {
                                float xx = acc1[mt][nt][r] + bias;
                                float ge = 0.5f * xx * (1.f + erff(xx * 0.70710678118654752f));
                                unsigned short hb = f2bf(ge);
                                arena[OFFT + row * AS + nl] = hb;
                                arena[OFFT + row * AS + 128 + nl] = f2bf(ge - bf2f(hb));
                            }
                        }
                }
                __syncthreads();   // t half visible
                gemm_bt<2, 4>(arena + OFFT, AS, 128, wsw + WT2 + i * 32768, 256, 0, hf * 4, wave, lane, acc2);
                __syncthreads();   // done reading t before next half overwrites
            }
            const float* b2 = b_fc2 + i * C;
            #pragma unroll
            for (int nt = 0; nt < 2; ++nt) {
                int n = (wave * 2 + nt) * 16 + m16;
                float bias = b2[n];
                #pragma unroll
                for (int mt = 0; mt < MT; ++mt)
                    #pragma unroll
                    for (int r = 0; r < 4; ++r) {
                        int row = mt * 16 + q4 * 4 + r;
                        if (row < ROWS) h_s[row * LS + n] += acc2[mt][nt][r] + bias;
                    }
            }
        }
        __syncthreads();
    }

    // ---- final LN -> out ----
    ln_stage<2>(h_s, nullptr, nullptr, fn_g, fn_b, nullptr, 0.f, out, blk * ROWS, wave, lane);
}

extern "C" void kernel_launch(void* const* d_in, const int* in_sizes, int n_in,
                              void* d_out, int out_size, void* d_ws, size_t ws_size,
                              hipStream_t stream) {
    const float* x       = (const float*)d_in[0];
    const float* adj     = (const float*)d_in[1];
    const float* w_embed = (const float*)d_in[2];
    const float* b_embed = (const float*)d_in[3];
    const float* pos     = (const float*)d_in[4];
    const float* ln1_g   = (const float*)d_in[5];
    const float* ln1_b   = (const float*)d_in[6];
    const float* w_qkv   = (const float*)d_in[7];
    const float* b_qkv   = (const float*)d_in[8];
    const float* w_gate  = (const float*)d_in[9];
    const float* b_gate  = (const float*)d_in[10];
    const float* w_proj  = (const float*)d_in[11];
    const float* b_proj  = (const float*)d_in[12];
    const float* ln2_g   = (const float*)d_in[13];
    const float* ln2_b   = (const float*)d_in[14];
    const float* w_fc1   = (const float*)d_in[15];
    const float* b_fc1   = (const float*)d_in[16];
    const float* w_fc2   = (const float*)d_in[17];
    const float* b_fc2   = (const float*)d_in[18];
    const float* fn_g    = (const float*)d_in[19];
    const float* fn_b    = (const float*)d_in[20];
    unsigned short* ws   = (unsigned short*)d_ws;   // 2 MiB
    float* out = (float*)d_out;

    prep_wt<<<2048, 256, 0, stream>>>(w_qkv, w_proj, w_fc1, w_fc2, ws);
    pose3d_r7<<<3888, 256, 0, stream>>>(x, adj, w_embed, b_embed, pos,
        ln1_g, ln1_b, b_qkv, w_gate, b_gate, b_proj, ln2_g, ln2_b,
        b_fc1, b_fc2, fn_g, fn_b, ws, out);
}